// Round 1
// baseline (219.916 us; speedup 1.0000x reference)
//
#include <hip/hip_runtime.h>
#include <math.h>

// S4-NPLR kernel generation, MI355X (gfx950).
// K_hat[d,k] = (2/(1+z_k)) * (CRB - CRP*PRB/(1+PRP)),  R = 1/(g[d,k]-Lam[d,n])
// K = Re(ifft(K_hat)) ; plus passthrough of D.
//
// Fused design: one block per d (512 blocks, 256 threads).
//  Phase 1: Cauchy sums over n=64 for 16 k's/thread (2 chunks of 8, register-blocked),
//           epilogue writes K_hat into LDS at bit-reversed position.
//  Phase 2: in-place radix-2 DIT inverse FFT (12 stages) in LDS, write Re/4096.

#define DM 512
#define NS 64
#define LL 4096
#define THREADS 256
#define CHUNK 8   // k's per thread per chunk; 2 chunks * 8 * 256 = 4096

__global__ __launch_bounds__(THREADS) void s4_fused(
    const float* __restrict__ Lre, const float* __restrict__ Lim,
    const float* __restrict__ Pre, const float* __restrict__ Pim,
    const float* __restrict__ Bre, const float* __restrict__ Bim,
    const float* __restrict__ Cre, const float* __restrict__ Cim,
    const float* __restrict__ logdt,
    float* __restrict__ out)
{
    __shared__ float sLr[NS], sLi[NS];
    __shared__ float2 sw1[NS], sw2[NS], sw3[NS], sw4[NS];
    __shared__ float2 a[LL];   // 32 KB: K_hat row (bit-reversed), then FFT in-place

    const int d = blockIdx.x;
    const int t = threadIdx.x;

    // ---- per-(d,n) weights into LDS ----
    if (t < NS) {
        const int n = t;
        const int i = d * NS + n;
        float lr = Lre[i];
        // stable softplus: max(x,0) + log1p(exp(-|x|))
        float sp = fmaxf(lr, 0.0f) + log1pf(expf(-fabsf(lr)));
        sLr[n] = -sp;
        sLi[n] = Lim[i];
        float pr = Pre[i], pi = Pim[i];
        float br = Bre[i], bi = Bim[i];
        float cr = Cre[i], ci = Cim[i];
        // w1 = conj(P)*B, w2 = conj(P)*P, w3 = conj(C)*B, w4 = conj(C)*P
        sw1[n] = make_float2(pr*br + pi*bi, pr*bi - pi*br);
        sw2[n] = make_float2(pr*pr + pi*pi, 0.0f);
        sw3[n] = make_float2(cr*br + ci*bi, cr*bi - ci*br);
        sw4[n] = make_float2(cr*pr + ci*pi, cr*pi - ci*pr);
    }
    __syncthreads();

    const float tdt = 2.0f / expf(logdt[d]);
    const float EPS = 1.1920929e-7f;   // finfo(float32).eps

    for (int c = 0; c < 2; ++c) {
        float gr[CHUNK], gi[CHUNK], fr[CHUNK], fi[CHUNK];
        float a1r[CHUNK], a1i[CHUNK], a2r[CHUNK], a2i[CHUNK];
        float a3r[CHUNK], a3i[CHUNK], a4r[CHUNK], a4i[CHUNK];

        // ---- per-k setup: z, clamped denom, g, final factor f = 2/denom ----
        #pragma unroll
        for (int kk = 0; kk < CHUNK; ++kk) {
            const int k = c * (LL/2) + kk * THREADS + t;
            float ang = -((float)k * 6.28318530717958647692f) * (1.0f / 4096.0f);
            float zr, zi;
            sincosf(ang, &zi, &zr);
            float dr = 1.0f + zr, di = zi;
            bool small = sqrtf(dr*dr + di*di) < EPS;
            dr = small ? EPS : dr;
            di = small ? 0.0f : di;
            float inv = 1.0f / (dr*dr + di*di);
            float nr = 1.0f - zr, ni = -zi;
            gr[kk] = tdt * (nr*dr + ni*di) * inv;
            gi[kk] = tdt * (ni*dr - nr*di) * inv;
            fr[kk] =  2.0f * dr * inv;
            fi[kk] = -2.0f * di * inv;
            a1r[kk]=0.f; a1i[kk]=0.f; a2r[kk]=0.f; a2i[kk]=0.f;
            a3r[kk]=0.f; a3i[kk]=0.f; a4r[kk]=0.f; a4i[kk]=0.f;
        }

        // ---- Cauchy sums over n ----
        for (int n = 0; n < NS; ++n) {
            const float lr = sLr[n], li = sLi[n];
            const float2 w1 = sw1[n], w2 = sw2[n], w3 = sw3[n], w4 = sw4[n];
            #pragma unroll
            for (int kk = 0; kk < CHUNK; ++kk) {
                float ar = gr[kk] - lr;
                float ai = gi[kk] - li;
                float inv = __builtin_amdgcn_rcpf(ar*ar + ai*ai);
                float rr =  ar * inv;          // r = 1/(ar + i*ai)
                float ri = -ai * inv;
                a1r[kk] += w1.x*rr - w1.y*ri;  a1i[kk] += w1.x*ri + w1.y*rr;
                a2r[kk] += w2.x*rr - w2.y*ri;  a2i[kk] += w2.x*ri + w2.y*rr;
                a3r[kk] += w3.x*rr - w3.y*ri;  a3i[kk] += w3.x*ri + w3.y*rr;
                a4r[kk] += w4.x*rr - w4.y*ri;  a4i[kk] += w4.x*ri + w4.y*rr;
            }
        }

        // ---- Woodbury epilogue; write K_hat bit-reversed into LDS ----
        #pragma unroll
        for (int kk = 0; kk < CHUNK; ++kk) {
            const int k = c * (LL/2) + kk * THREADS + t;
            float opr = 1.0f + a2r[kk], opi = a2i[kk];     // 1 + PRP
            float inv = 1.0f / (opr*opr + opi*opi);
            float qr = (a1r[kk]*opr + a1i[kk]*opi) * inv;  // PRB/(1+PRP)
            float qi = (a1i[kk]*opr - a1r[kk]*opi) * inv;
            float crr = a4r[kk]*qr - a4i[kk]*qi;           // CRP * q
            float cri = a4r[kk]*qi + a4i[kk]*qr;
            float numr = a3r[kk] - crr;                    // CRB - corr
            float numi = a3i[kk] - cri;
            float khr = fr[kk]*numr - fi[kk]*numi;         // (2/denom)*num
            float khi = fr[kk]*numi + fi[kk]*numr;
            int r = (int)(__brev((unsigned)k) >> 20);      // 12-bit reversal
            a[r] = make_float2(khr, khi);
        }
    }
    __syncthreads();

    // ---- radix-2 DIT inverse FFT (sign +1), in place ----
    for (int stage = 1; stage <= 12; ++stage) {
        const int half = 1 << (stage - 1);
        const float angb = 6.28318530717958647692f / (float)(1 << stage);
        for (int i = t; i < LL/2; i += THREADS) {
            int j = i & (half - 1);
            int idx = ((i >> (stage - 1)) << stage) + j;
            float wi, wr;
            sincosf(angb * (float)j, &wi, &wr);
            float2 u = a[idx];
            float2 v = a[idx + half];
            float vr = v.x*wr - v.y*wi;
            float vi = v.x*wi + v.y*wr;
            a[idx]        = make_float2(u.x + vr, u.y + vi);
            a[idx + half] = make_float2(u.x - vr, u.y - vi);
        }
        __syncthreads();
    }

    // ---- write Re(ifft)/L ----
    const float scale = 1.0f / (float)LL;
    for (int i = t; i < LL; i += THREADS) {
        out[(size_t)d * LL + i] = a[i].x * scale;
    }
}

__global__ void copy_d(const float* __restrict__ Din, float* __restrict__ out)
{
    int i = threadIdx.x + blockIdx.x * blockDim.x;
    if (i < DM) out[(size_t)DM * LL + i] = Din[i];
}

extern "C" void kernel_launch(void* const* d_in, const int* in_sizes, int n_in,
                              void* d_out, int out_size, void* d_ws, size_t ws_size,
                              hipStream_t stream)
{
    const float* Lre   = (const float*)d_in[0];
    const float* Lim   = (const float*)d_in[1];
    const float* Pre   = (const float*)d_in[2];
    const float* Pim   = (const float*)d_in[3];
    const float* Bre   = (const float*)d_in[4];
    const float* Bim   = (const float*)d_in[5];
    const float* Cre   = (const float*)d_in[6];
    const float* Cim   = (const float*)d_in[7];
    const float* Dvec  = (const float*)d_in[8];
    const float* logdt = (const float*)d_in[9];
    float* out = (float*)d_out;

    s4_fused<<<DM, THREADS, 0, stream>>>(Lre, Lim, Pre, Pim, Bre, Bim,
                                         Cre, Cim, logdt, out);
    copy_d<<<1, DM, 0, stream>>>(Dvec, out);
}

// Round 2
// 160.534 us; speedup vs baseline: 1.3699x; 1.3699x over previous
//
#include <hip/hip_runtime.h>
#include <math.h>

// S4-NPLR kernel generation, MI355X (gfx950) — round 2.
//
// Math: g_k = i*nu, nu = (2/dt)*tan(pi*k/L);  2/(1+z_k) = 1 + i*tan(pi*k/L).
// Poles come in adjacent conjugate pairs (dgeev) -> pair-merged rational form:
//   w_a/(g-la) + w_b/(g-lb) = (c1*g - c0) / (g^2 - s*g + q),  s,q real.
// Mirror freq k' = L-k has g' = -i*nu: denominator conjugates -> shared rcp.
// Both sides merged on the fly into hermitian part H[k] = (Khat[k]+conj(Khat[L-k]))/2,
// then K = IFFT(H) via real-pack: half-length (2048) complex IFFT.
//
// kernel1: 2048 blocks(=512 d x 4 quarters) x 256 thr -> H[d][0..2047] into d_out,
//          Nyquist H[2048] (clamped-denom branch) into d_out's D-slot (stash).
// kernel2: 512 blocks x 512 thr: pack-unpack + 11-stage LDS IFFT + write K, D.

#define DM 512
#define NS 64
#define NP 32
#define LL 4096
#define HM 2048
#define PI_F 3.14159274101257324f

__device__ inline float softplusf(float x) {
    return fmaxf(x, 0.0f) + log1pf(expf(-fabsf(x)));
}

__device__ inline float2 woodbury(float a1r, float a1i, float a2r, float a2i,
                                  float a3r, float a3i, float a4r, float a4i,
                                  float tau) {
    float opr = 1.0f + a2r, opi = a2i;            // 1 + PRP
    float inv = 1.0f / (opr*opr + opi*opi);
    float qr = (a1r*opr + a1i*opi) * inv;         // PRB/(1+PRP)
    float qi = (a1i*opr - a1r*opi) * inv;
    float cr = a4r*qr - a4i*qi;                   // CRP * q
    float ci = a4r*qi + a4i*qr;
    float nr = a3r - cr, ni = a3i - ci;           // CRB - corr
    return make_float2(nr - tau*ni, ni + tau*nr); // (1 + i*tau) * num
}

__global__ __launch_bounds__(256, 8) void s4_cauchy(
    const float* __restrict__ Lre, const float* __restrict__ Lim,
    const float* __restrict__ Pre, const float* __restrict__ Pim,
    const float* __restrict__ Bre, const float* __restrict__ Bim,
    const float* __restrict__ Cre, const float* __restrict__ Cim,
    const float* __restrict__ logdt,
    float* __restrict__ out)
{
    // per pair m: pc[m*5+0] = (mtwo=-(la+lb).re, q=Re(la*lb), 0, 0)
    //             pc[m*5+1+j] = (c1r, c1i, -c0r, -c0i) for weights j=0..3
    __shared__ float4 pc[NP * 5];

    const int bx = blockIdx.x;
    const int d  = bx >> 2;
    const int q4 = bx & 3;
    const int t  = threadIdx.x;

    const float tdt = 2.0f / expf(logdt[d]);

    if (t < NP) {
        const int m  = t;
        const int ia = d * NS + 2 * m;
        const int ib = ia + 1;
        float lar = -softplusf(Lre[ia]), lai = Lim[ia];
        float lbr = -softplusf(Lre[ib]), lbi = Lim[ib];
        float par = Pre[ia], pai = Pim[ia], pbr = Pre[ib], pbi = Pim[ib];
        float bar_ = Bre[ia], bai = Bim[ia], bbr = Bre[ib], bbi = Bim[ib];
        float car = Cre[ia], cai = Cim[ia], cbr = Cre[ib], cbi = Cim[ib];

        pc[m*5] = make_float4(-(lar + lbr), lar*lbr - lai*lbi, 0.0f, 0.0f);

        float war[4], wai[4], wbr_[4], wbi_[4];
        // w1 = conj(P)B, w2 = conj(P)P, w3 = conj(C)B, w4 = conj(C)P
        war[0] = par*bar_ + pai*bai;  wai[0] = par*bai - pai*bar_;
        war[1] = par*par + pai*pai;   wai[1] = 0.0f;
        war[2] = car*bar_ + cai*bai;  wai[2] = car*bai - cai*bar_;
        war[3] = car*par + cai*pai;   wai[3] = car*pai - cai*par;
        wbr_[0] = pbr*bbr + pbi*bbi;  wbi_[0] = pbr*bbi - pbi*bbr;
        wbr_[1] = pbr*pbr + pbi*pbi;  wbi_[1] = 0.0f;
        wbr_[2] = cbr*bbr + cbi*bbi;  wbi_[2] = cbr*bbi - cbi*bbr;
        wbr_[3] = cbr*pbr + cbi*pbi;  wbi_[3] = cbr*pbi - cbi*pbr;

        #pragma unroll
        for (int j = 0; j < 4; ++j) {
            float c1r = war[j] + wbr_[j];
            float c1i = wai[j] + wbi_[j];
            // c0 = wa*lb + wb*la
            float c0r = war[j]*lbr - wai[j]*lbi + wbr_[j]*lar - wbi_[j]*lai;
            float c0i = war[j]*lbi + wai[j]*lbr + wbr_[j]*lai + wbi_[j]*lar;
            pc[m*5 + 1 + j] = make_float4(c1r, c1i, -c0r, -c0i);
        }
    }

    // ---- Nyquist term (clamped-denom branch), wave 0 of q==0 blocks ----
    if (q4 == 0 && t < 64) {
        const int n = t;
        const int i = d * NS + n;
        float lr = -softplusf(Lre[i]), li = Lim[i];
        float pr_ = Pre[i], pi_ = Pim[i];
        float br_ = Bre[i], bi_ = Bim[i];
        float cr_ = Cre[i], ci_ = Cim[i];
        float w1r = pr_*br_ + pi_*bi_, w1i = pr_*bi_ - pi_*br_;
        float w2r = pr_*pr_ + pi_*pi_, w2i = 0.0f;
        float w3r = cr_*br_ + ci_*bi_, w3i = cr_*bi_ - ci_*br_;
        float w4r = cr_*pr_ + ci_*pi_, w4i = cr_*pi_ - ci_*pr_;
        // z = (-1, 8.742278e-8), denom clamped to (eps, 0); g = tdt*(1-z)/eps
        float gr = tdt * 16777216.0f;                     // tdt * 2/eps
        float gi = -tdt * (8.7422777e-8f * 8388608.0f);   // -tdt * zi/eps
        float ar = gr - lr, ai = gi - li;
        float inv = 1.0f / (ar*ar + ai*ai);
        float rr = ar*inv, ri = -ai*inv;
        float s1r = w1r*rr - w1i*ri, s1i = w1r*ri + w1i*rr;
        float s2r = w2r*rr - w2i*ri, s2i = w2r*ri + w2i*rr;
        float s3r = w3r*rr - w3i*ri, s3i = w3r*ri + w3i*rr;
        float s4r = w4r*rr - w4i*ri, s4i = w4r*ri + w4i*rr;
        #pragma unroll
        for (int msk = 32; msk; msk >>= 1) {
            s1r += __shfl_xor(s1r, msk); s1i += __shfl_xor(s1i, msk);
            s2r += __shfl_xor(s2r, msk); s2i += __shfl_xor(s2i, msk);
            s3r += __shfl_xor(s3r, msk); s3i += __shfl_xor(s3i, msk);
            s4r += __shfl_xor(s4r, msk); s4i += __shfl_xor(s4i, msk);
        }
        if (t == 0) {
            float2 kny = woodbury(s1r, s1i, s2r, s2i, s3r, s3i, s4r, s4i, 0.0f);
            out[(size_t)DM * LL + d] = 16777216.0f * kny.x;  // (2/eps)*num, real part
        }
    }
    __syncthreads();

    float2* __restrict__ Hrow = (float2*)out + (size_t)d * HM;

    for (int it = 0; it < 2; ++it) {
        const int k = q4 * 512 + it * 256 + t;       // 0..2047
        float sn, cs;
        sincosf((float)k * (PI_F / 4096.0f), &sn, &cs);
        const float tau = sn * __builtin_amdgcn_rcpf(cs);
        const float nu  = tdt * tau;
        const float nu2 = nu * nu;

        float apr[4] = {0,0,0,0}, api[4] = {0,0,0,0};
        float amr[4] = {0,0,0,0}, ami[4] = {0,0,0,0};

        for (int m = 0; m < NP; ++m) {
            float4 h = pc[m*5];
            float den_r = h.y - nu2;
            float den_i = h.x * nu;
            float d2  = den_r*den_r + den_i*den_i;
            float inv = __builtin_amdgcn_rcpf(d2);
            float pr =  den_r * inv;
            float pi = -den_i * inv;
            #pragma unroll
            for (int j = 0; j < 4; ++j) {
                float4 w = pc[m*5 + 1 + j];
                float t1 = w.y * nu, t2 = w.x * nu;
                float nrp = w.z - t1, nip = w.w + t2;   // num(+)
                float nrm = w.z + t1, nim = w.w - t2;   // num(-)
                apr[j] += nrp*pr - nip*pi;  api[j] += nrp*pi + nip*pr;
                amr[j] += nrm*pr + nim*pi;  ami[j] += nim*pr - nrm*pi;
            }
        }

        float2 kp = woodbury(apr[0],api[0],apr[1],api[1],apr[2],api[2],apr[3],api[3],  tau);
        float2 km = woodbury(amr[0],ami[0],amr[1],ami[1],amr[2],ami[2],amr[3],ami[3], -tau);
        Hrow[k] = make_float2(0.5f*(kp.x + km.x), 0.5f*(kp.y - km.y));
    }
}

__global__ __launch_bounds__(512) void s4_ifft(
    float* __restrict__ out, const float* __restrict__ Din)
{
    __shared__ float2 zb[HM];
    __shared__ float2 tw[1024];

    const int d = blockIdx.x;
    const int t = threadIdx.x;
    const float2* Hrow = (const float2*)out + (size_t)d * HM;
    const float s = 1.0f / 4096.0f;

    // twiddle table: tw[j] = e^{+2*pi*i*j/2048}
    for (int j = t; j < 1024; j += 512) {
        float sn, cs;
        sincosf((float)j * (6.28318530717958647692f / 2048.0f), &sn, &cs);
        tw[j] = make_float2(cs, sn);
    }

    // ---- pack-unpack: Z[k] = [(X[k]+X[k+M]) + i*t_k*(X[k]-X[k+M])] / 4096 ----
    #pragma unroll
    for (int pp = 0; pp < 2; ++pp) {
        const int pk = t + pp * 512;                 // 0..1023
        if (pk == 0) {
            float2 A = Hrow[0];
            float h2 = out[(size_t)DM * LL + d];     // stashed H[2048] (real)
            zb[0] = make_float2(s * (A.x + h2), s * (A.x - h2));
        } else {
            const int mk = HM - pk;
            float2 A  = Hrow[pk];
            float2 Bc = Hrow[mk];
            float sn, cs;
            sincosf((float)pk * (6.28318530717958647692f / 4096.0f), &sn, &cs);
            float Srr = A.x + Bc.x, Sri = A.y - Bc.y;     // A + conj(B)
            float Dvr = A.x - Bc.x, Dvi = A.y + Bc.y;     // A - conj(B)
            float TDr = cs*Dvr - sn*Dvi;
            float TDi = cs*Dvi + sn*Dvr;
            int rp = (int)(__brev((unsigned)pk) >> 21);
            int rm = (int)(__brev((unsigned)mk) >> 21);
            zb[rp] = make_float2(s * (Srr - TDi), s * ( Sri + TDr));
            zb[rm] = make_float2(s * (Srr + TDi), s * (-Sri + TDr));
        }
    }
    if (t == 0) {
        float2 A = Hrow[1024];
        zb[(int)(__brev(1024u) >> 21)] = make_float2(2.0f*s*A.x, -2.0f*s*A.y);
    }
    __syncthreads();

    // ---- 11-stage radix-2 DIT inverse FFT (twiddles e^{+i...} from table) ----
    for (int st = 1; st <= 11; ++st) {
        const int half = 1 << (st - 1);
        #pragma unroll
        for (int b = t; b < 1024; b += 512) {
            int j = b & (half - 1);
            int base = ((b >> (st - 1)) << st) + j;
            float2 w = tw[j << (11 - st)];
            float2 u = zb[base];
            float2 v = zb[base + half];
            float vr = v.x*w.x - v.y*w.y;
            float vi = v.x*w.y + v.y*w.x;
            zb[base]        = make_float2(u.x + vr, u.y + vi);
            zb[base + half] = make_float2(u.x - vr, u.y - vi);
        }
        __syncthreads();
    }

    // x[2n] = Re z[n], x[2n+1] = Im z[n] -> contiguous float2 row
    float2* o2 = (float2*)out + (size_t)d * HM;
    for (int n = t; n < HM; n += 512) o2[n] = zb[n];
    if (t == 0) out[(size_t)DM * LL + d] = Din[d];
}

extern "C" void kernel_launch(void* const* d_in, const int* in_sizes, int n_in,
                              void* d_out, int out_size, void* d_ws, size_t ws_size,
                              hipStream_t stream)
{
    const float* Lre   = (const float*)d_in[0];
    const float* Lim   = (const float*)d_in[1];
    const float* Pre   = (const float*)d_in[2];
    const float* Pim   = (const float*)d_in[3];
    const float* Bre   = (const float*)d_in[4];
    const float* Bim   = (const float*)d_in[5];
    const float* Cre   = (const float*)d_in[6];
    const float* Cim   = (const float*)d_in[7];
    const float* Dvec  = (const float*)d_in[8];
    const float* logdt = (const float*)d_in[9];
    float* out = (float*)d_out;

    s4_cauchy<<<DM * 4, 256, 0, stream>>>(Lre, Lim, Pre, Pim, Bre, Bim,
                                          Cre, Cim, logdt, out);
    s4_ifft<<<DM, 512, 0, stream>>>(out, Dvec);
}